// Round 1
// baseline (1019.152 us; speedup 1.0000x reference)
//
#include <hip/hip_runtime.h>
#include <cstdint>
#include <cstddef>

typedef unsigned short u16;
typedef __attribute__((ext_vector_type(8))) short short8;
typedef __attribute__((ext_vector_type(4))) float f32x4;

#define DEV __device__ __forceinline__

DEV float bf2f(u16 v) { union { unsigned u; float f; } x; x.u = ((unsigned)v) << 16; return x.f; }
DEV u16 f2bf(float f) {
  union { float f; unsigned u; } x; x.f = f;
  unsigned r = x.u + 0x7fffu + ((x.u >> 16) & 1u);
  return (u16)(r >> 16);
}

DEV void gload_lds16(const void* g, void* l) {
  __builtin_amdgcn_global_load_lds((const __attribute__((address_space(1))) void*)g,
                                   (__attribute__((address_space(3))) void*)l, 16, 0, 0);
}

// ---------- transpose f32 (R x C) -> bf16 (C x R), batched over z ----------
__global__ __launch_bounds__(256) void transpose_w_kernel(
    const float* __restrict__ in, u16* __restrict__ out, int R, int C)
{
  __shared__ float tile[32][33];
  const int tx = threadIdx.x, ty = threadIdx.y;
  const int c0 = blockIdx.x * 32, r0 = blockIdx.y * 32;
  const float* inb = in + (size_t)blockIdx.z * R * C;
  u16* outb = out + (size_t)blockIdx.z * R * C;
#pragma unroll
  for (int i = 0; i < 4; ++i)
    tile[ty + i * 8][tx] = inb[(size_t)(r0 + ty + i * 8) * C + c0 + tx];
  __syncthreads();
#pragma unroll
  for (int i = 0; i < 4; ++i)
    outb[(size_t)(c0 + ty + i * 8) * R + r0 + tx] = f2bf(tile[tx][ty + i * 8]);
}

__global__ __launch_bounds__(256) void concat_bias_kernel(
    const float* __restrict__ qb, const float* __restrict__ kb,
    const float* __restrict__ vb, float* __restrict__ bias)
{
  const int i = blockIdx.x * 256 + threadIdx.x;
  if (i < 2048) bias[i] = qb[i];
  else if (i < 2304) bias[i] = kb[i - 2048];
  else if (i < 2560) bias[i] = vb[i - 2304];
}

// ---------- RMSNorm: f32 row (2048) -> bf16 ----------
__global__ __launch_bounds__(256) void rmsnorm_kernel(
    const float* __restrict__ x, const float* __restrict__ scale, u16* __restrict__ out)
{
  const int row = blockIdx.x, tid = threadIdx.x;
  const float* xr = x + (size_t)row * 2048;
  const float4 v0 = *(const float4*)&xr[tid * 8];
  const float4 v1 = *(const float4*)&xr[tid * 8 + 4];
  float ss = v0.x * v0.x + v0.y * v0.y + v0.z * v0.z + v0.w * v0.w +
             v1.x * v1.x + v1.y * v1.y + v1.z * v1.z + v1.w * v1.w;
#pragma unroll
  for (int d = 32; d > 0; d >>= 1) ss += __shfl_down(ss, d);
  __shared__ float red[4];
  if ((tid & 63) == 0) red[tid >> 6] = ss;
  __syncthreads();
  const float tot = red[0] + red[1] + red[2] + red[3];
  const float inv = rsqrtf(tot * (1.f / 2048.f) + 1e-6f);
  const float* sc = scale + tid * 8;
  short8 ov;
  ov[0] = (short)f2bf(v0.x * inv * sc[0]); ov[1] = (short)f2bf(v0.y * inv * sc[1]);
  ov[2] = (short)f2bf(v0.z * inv * sc[2]); ov[3] = (short)f2bf(v0.w * inv * sc[3]);
  ov[4] = (short)f2bf(v1.x * inv * sc[4]); ov[5] = (short)f2bf(v1.y * inv * sc[5]);
  ov[6] = (short)f2bf(v1.z * inv * sc[6]); ov[7] = (short)f2bf(v1.w * inv * sc[7]);
  *(short8*)&out[(size_t)row * 2048 + tid * 8] = ov;
}

// ---------- GEMM: C(MxN) = A(MxK,bf16) @ Bt(NxK,bf16)^T, m97 structure ----------
// MODE 0: C f32 = acc + bias[col]; MODE 1: C f32 = acc + aux[idx]; MODE 2: C bf16 = acc
template <int MODE>
__global__ __launch_bounds__(256) void gemm_bt_kernel(
    const u16* __restrict__ A, const u16* __restrict__ Bt,
    void* C, const float* aux, int M, int N, int K)
{
  __shared__ u16 As[128 * 64];
  __shared__ u16 Bs[128 * 64];
  const int tid = threadIdx.x;
  const int wave = tid >> 6, lane = tid & 63, lo = lane & 15, hi = lane >> 4;
  const int wm = wave >> 1, wn = wave & 1;
  const int row0 = blockIdx.y * 128, col0 = blockIdx.x * 128;

  const f32x4 fz = {0.f, 0.f, 0.f, 0.f};
  f32x4 acc[4][4];
#pragma unroll
  for (int a = 0; a < 4; ++a)
#pragma unroll
    for (int b = 0; b < 4; ++b) acc[a][b] = fz;

  const u16* Ag = A + (size_t)(row0 + (tid >> 3)) * K + (tid & 7) * 8;
  const u16* Bg = Bt + (size_t)(col0 + (tid >> 3)) * K + (tid & 7) * 8;
  u16* lA = &As[wave * 512];
  u16* lB = &Bs[wave * 512];

  for (int kt = 0; kt < K; kt += 64) {
#pragma unroll
    for (int i = 0; i < 4; ++i) {
      gload_lds16(Ag + (size_t)i * 32 * K + kt, lA + i * 2048);
      gload_lds16(Bg + (size_t)i * 32 * K + kt, lB + i * 2048);
    }
    __syncthreads();
#pragma unroll
    for (int kc = 0; kc < 2; ++kc) {
      short8 af[4], bfr[4];
#pragma unroll
      for (int mt = 0; mt < 4; ++mt)
        af[mt] = *(const short8*)&As[(wm * 64 + mt * 16 + lo) * 64 + kc * 32 + hi * 8];
#pragma unroll
      for (int nt = 0; nt < 4; ++nt)
        bfr[nt] = *(const short8*)&Bs[(wn * 64 + nt * 16 + lo) * 64 + kc * 32 + hi * 8];
#pragma unroll
      for (int mt = 0; mt < 4; ++mt)
#pragma unroll
        for (int nt = 0; nt < 4; ++nt)
          acc[mt][nt] = __builtin_amdgcn_mfma_f32_16x16x32_bf16(af[mt], bfr[nt], acc[mt][nt], 0, 0, 0);
    }
    __syncthreads();
  }

  float* Cf = (float*)C;
  u16* Ch = (u16*)C;
#pragma unroll
  for (int mt = 0; mt < 4; ++mt) {
#pragma unroll
    for (int nt = 0; nt < 4; ++nt) {
      const int col = col0 + wn * 64 + nt * 16 + lo;
#pragma unroll
      for (int j = 0; j < 4; ++j) {
        const int row = row0 + wm * 64 + mt * 16 + hi * 4 + j;
        const size_t idx = (size_t)row * N + col;
        const float v = acc[mt][nt][j];
        if (MODE == 0) Cf[idx] = v + aux[col];
        else if (MODE == 1) Cf[idx] = v + aux[idx];
        else Ch[idx] = f2bf(v);
      }
    }
  }
}

// ---------- RoPE q: qkv f32 (4096 x 2560) -> Qb bf16 (B,N,T,H), scaled ----------
__global__ __launch_bounds__(256) void rope_q_kernel(
    const float* __restrict__ qkv, const int* __restrict__ pos, u16* __restrict__ Qb)
{
  const int idx = blockIdx.x * 256 + threadIdx.x;  // 4096*1024
  const int bt = idx >> 10;
  const int rem = idx & 1023;
  const int n = rem >> 6, hp = rem & 63;
  const int t = bt & 2047, b = bt >> 11;
  const float x1 = qkv[(size_t)bt * 2560 + n * 128 + hp];
  const float x2 = qkv[(size_t)bt * 2560 + n * 128 + hp + 64];
  const float inv = exp2f((float)hp * (-19.931568569324174f / 64.f));
  const float ang = (float)pos[t] * inv;
  float s, c;
  sincosf(ang, &s, &c);
  const float sc = 0.08838834764831845f;  // 1/sqrt(128)
  const size_t base = ((size_t)(b * 16 + n) * 2048 + t) * 128 + hp;
  Qb[base] = f2bf((x1 * c - x2 * s) * sc);
  Qb[base + 64] = f2bf((x2 * c + x1 * s) * sc);
}

__global__ __launch_bounds__(256) void rope_k_kernel(
    const float* __restrict__ qkv, const int* __restrict__ pos, u16* __restrict__ Kb)
{
  const int idx = blockIdx.x * 256 + threadIdx.x;  // 4096*128
  const int bt = idx >> 7;
  const int rem = idx & 127;
  const int kh = rem >> 6, hp = rem & 63;
  const int t = bt & 2047, b = bt >> 11;
  const float x1 = qkv[(size_t)bt * 2560 + 2048 + kh * 128 + hp];
  const float x2 = qkv[(size_t)bt * 2560 + 2048 + kh * 128 + hp + 64];
  const float inv = exp2f((float)hp * (-19.931568569324174f / 64.f));
  const float ang = (float)pos[t] * inv;
  float s, c;
  sincosf(ang, &s, &c);
  const size_t base = ((size_t)(b * 2 + kh) * 2048 + t) * 128 + hp;
  Kb[base] = f2bf(x1 * c - x2 * s);
  Kb[base + 64] = f2bf(x2 * c + x1 * s);
}

// ---------- V: qkv f32 -> Vt bf16 (B,KH,H,T) transposed ----------
__global__ __launch_bounds__(256) void v_store_kernel(
    const float* __restrict__ qkv, u16* __restrict__ Vt)
{
  const int idx = blockIdx.x * 256 + threadIdx.x;  // 4096*256
  const int bt = idx >> 8;
  const int rem = idx & 255;
  const int kh = rem >> 7, hh = rem & 127;
  const int t = bt & 2047, b = bt >> 11;
  const float v = qkv[(size_t)bt * 2560 + 2304 + kh * 128 + hh];
  Vt[((size_t)((b * 2 + kh) * 128 + hh)) * 2048 + t] = f2bf(v);
}

// ---------- flash attention, causal, GQA group 8 ----------
__global__ __launch_bounds__(256) void attn_kernel(
    const u16* __restrict__ Qb, const u16* __restrict__ Kb,
    const u16* __restrict__ Vt, u16* __restrict__ Out)
{
  __shared__ u16 Ks[64 * 128];
  __shared__ u16 Vs[128 * 64];
  __shared__ u16 Ps[4][16 * 64];
  const int tid = threadIdx.x;
  const int wave = tid >> 6, lane = tid & 63, lo = lane & 15, hi = lane >> 4;
  const int q0 = (int)(gridDim.x - 1 - blockIdx.x) * 64;  // heavy tiles first
  const int bn = blockIdx.y;
  const int b = bn >> 4, n = bn & 15, kh = n >> 3;

  const u16* qptr = Qb + ((size_t)((b * 16 + n) * 2048) + q0 + wave * 16 + lo) * 128;
  short8 qf[4];
#pragma unroll
  for (int kc = 0; kc < 4; ++kc) qf[kc] = *(const short8*)&qptr[kc * 32 + hi * 8];

  const f32x4 fz = {0.f, 0.f, 0.f, 0.f};
  float m_r[4], l_r[4];
  f32x4 oacc[8];
#pragma unroll
  for (int j = 0; j < 4; ++j) { m_r[j] = -1e30f; l_r[j] = 0.f; }
#pragma unroll
  for (int ht = 0; ht < 8; ++ht) oacc[ht] = fz;

  const u16* kg = Kb + (size_t)(b * 2 + kh) * 2048 * 128;
  const u16* vg = Vt + (size_t)(b * 2 + kh) * 128 * 2048;
  const int nblk = q0 / 64 + 1;

  u16* lK = &Ks[wave * 512];
  u16* lV = &Vs[wave * 512];
  const int kr = tid >> 4, kcc = (tid & 15) * 8;
  const int vr = tid >> 3, vcc = (tid & 7) * 8;

  for (int sb = 0; sb < nblk; ++sb) {
    const int s0 = sb * 64;
    __syncthreads();
#pragma unroll
    for (int i = 0; i < 4; ++i) {
      gload_lds16(kg + (size_t)(s0 + i * 16 + kr) * 128 + kcc, lK + i * 2048);
      gload_lds16(vg + (size_t)(i * 32 + vr) * 2048 + s0 + vcc, lV + i * 2048);
    }
    __syncthreads();

    float sall[4][4];
#pragma unroll
    for (int st = 0; st < 4; ++st) {
      f32x4 s = fz;
#pragma unroll
      for (int kc = 0; kc < 4; ++kc) {
        short8 kf = *(const short8*)&Ks[(st * 16 + lo) * 128 + kc * 32 + hi * 8];
        s = __builtin_amdgcn_mfma_f32_16x16x32_bf16(qf[kc], kf, s, 0, 0, 0);
      }
#pragma unroll
      for (int j = 0; j < 4; ++j) sall[st][j] = s[j];
    }

    if (sb == nblk - 1) {
#pragma unroll
      for (int st = 0; st < 4; ++st) {
        const int sg = s0 + st * 16 + lo;
#pragma unroll
        for (int j = 0; j < 4; ++j) {
          const int qg = q0 + wave * 16 + hi * 4 + j;
          if (sg > qg) sall[st][j] = -1e30f;
        }
      }
    }

    float alpha[4];
#pragma unroll
    for (int j = 0; j < 4; ++j) {
      float t = fmaxf(fmaxf(sall[0][j], sall[1][j]), fmaxf(sall[2][j], sall[3][j]));
      t = fmaxf(t, __shfl_xor(t, 1));
      t = fmaxf(t, __shfl_xor(t, 2));
      t = fmaxf(t, __shfl_xor(t, 4));
      t = fmaxf(t, __shfl_xor(t, 8));
      const float mnew = fmaxf(m_r[j], t);
      alpha[j] = __expf(m_r[j] - mnew);
      m_r[j] = mnew;
    }

    float rsum[4] = {0.f, 0.f, 0.f, 0.f};
#pragma unroll
    for (int st = 0; st < 4; ++st) {
#pragma unroll
      for (int j = 0; j < 4; ++j) {
        const float p = __expf(sall[st][j] - m_r[j]);
        rsum[j] += p;
        Ps[wave][(hi * 4 + j) * 64 + st * 16 + lo] = f2bf(p);
      }
    }
#pragma unroll
    for (int j = 0; j < 4; ++j) {
      float rs = rsum[j];
      rs += __shfl_xor(rs, 1);
      rs += __shfl_xor(rs, 2);
      rs += __shfl_xor(rs, 4);
      rs += __shfl_xor(rs, 8);
      l_r[j] = l_r[j] * alpha[j] + rs;
    }
#pragma unroll
    for (int ht = 0; ht < 8; ++ht) {
#pragma unroll
      for (int j = 0; j < 4; ++j) oacc[ht][j] *= alpha[j];
    }

    asm volatile("s_waitcnt lgkmcnt(0)" ::: "memory");
    __builtin_amdgcn_sched_barrier(0);

    const short8 pf0 = *(const short8*)&Ps[wave][lo * 64 + hi * 8];
    const short8 pf1 = *(const short8*)&Ps[wave][lo * 64 + 32 + hi * 8];
#pragma unroll
    for (int ht = 0; ht < 8; ++ht) {
      const short8 vf0 = *(const short8*)&Vs[(ht * 16 + lo) * 64 + hi * 8];
      const short8 vf1 = *(const short8*)&Vs[(ht * 16 + lo) * 64 + 32 + hi * 8];
      oacc[ht] = __builtin_amdgcn_mfma_f32_16x16x32_bf16(pf0, vf0, oacc[ht], 0, 0, 0);
      oacc[ht] = __builtin_amdgcn_mfma_f32_16x16x32_bf16(pf1, vf1, oacc[ht], 0, 0, 0);
    }
  }

#pragma unroll
  for (int j = 0; j < 4; ++j) {
    const float inv = 1.0f / l_r[j];
    const int trow = q0 + wave * 16 + hi * 4 + j;
    const size_t base = ((size_t)(b * 2048 + trow)) * 2048 + n * 128;
#pragma unroll
    for (int ht = 0; ht < 8; ++ht)
      Out[base + ht * 16 + lo] = f2bf(oacc[ht][j] * inv);
  }
}

// ---------- SwiGLU combine: g = silu(g) * u (bf16, in-place over g) ----------
__global__ __launch_bounds__(256) void silu_mul_kernel(
    u16* __restrict__ g, const u16* __restrict__ u)
{
  const size_t i = ((size_t)blockIdx.x * 256 + threadIdx.x) * 8;
  short8 gv = *(const short8*)&g[i];
  const short8 uv = *(const short8*)&u[i];
#pragma unroll
  for (int j = 0; j < 8; ++j) {
    const float xg = bf2f((u16)gv[j]);
    const float xu = bf2f((u16)uv[j]);
    const float s = xg / (1.f + __expf(-xg));
    gv[j] = (short)f2bf(s * xu);
  }
  *(short8*)&g[i] = gv;
}

extern "C" void kernel_launch(void* const* d_in, const int* in_sizes, int n_in,
                              void* d_out, int out_size, void* d_ws, size_t ws_size,
                              hipStream_t stream)
{
  const float* x      = (const float*)d_in[0];
  const int*   pos    = (const int*)d_in[1];
  const float* ln1    = (const float*)d_in[2];
  const float* q_w    = (const float*)d_in[3];
  const float* q_b    = (const float*)d_in[4];
  const float* k_w    = (const float*)d_in[5];
  const float* k_b    = (const float*)d_in[6];
  const float* v_w    = (const float*)d_in[7];
  const float* v_b    = (const float*)d_in[8];
  const float* o_w    = (const float*)d_in[9];
  const float* ln2    = (const float*)d_in[10];
  const float* gate_w = (const float*)d_in[11];
  const float* up_w   = (const float*)d_in[12];
  const float* down_w = (const float*)d_in[13];
  float* out = (float*)d_out;

  char* w = (char*)d_ws;
  u16* wqkv_t = (u16*)w;       w += 2560LL * 2048 * 2;   // (N*H+KH*H*2) x D, bf16
  u16* o_wt   = (u16*)w;       w += 2048LL * 2048 * 2;   // D x (N*H)
  u16* g_t    = (u16*)w;       w += 5504LL * 2048 * 2;   // I x D
  u16* u_t    = (u16*)w;       w += 5504LL * 2048 * 2;   // I x D
  u16* d_t    = (u16*)w;       w += 2048LL * 5504 * 2;   // D x I
  u16* hbuf   = (u16*)w;       w += 4096LL * 2048 * 2;   // h / h2 bf16
  float* bias_qkv = (float*)w; w += 2560 * 4;
  char* un = w;  // union region: phase1 (qkv/Qb/Kb/Vt/attn) then phase2 (g/u)
  float* qkv  = (float*)un;                                            // 4096x2560 f32
  u16*  Qb    = (u16*)(un + 41943040LL);                               // (B,N,T,H)
  u16*  Kb    = (u16*)(un + 41943040LL + 16777216LL);                  // (B,KH,T,H)
  u16*  Vt    = (u16*)(un + 41943040LL + 16777216LL + 2097152LL);      // (B,KH,H,T)
  u16*  attnb = (u16*)(un + 41943040LL + 16777216LL + 2097152LL + 2097152LL); // (B,T,N*H)
  u16*  gbuf  = (u16*)un;                                              // 4096x5504 bf16
  u16*  ubuf  = (u16*)(un + 45088768LL);                               // 4096x5504 bf16

  const dim3 tb(32, 8);
  // weight convert + transpose (f32 -> bf16, B^T layout)
  transpose_w_kernel<<<dim3(4, 64, 16), tb, 0, stream>>>(q_w, wqkv_t, 2048, 128);
  transpose_w_kernel<<<dim3(4, 64, 2),  tb, 0, stream>>>(k_w, wqkv_t + 2048LL * 2048, 2048, 128);
  transpose_w_kernel<<<dim3(4, 64, 2),  tb, 0, stream>>>(v_w, wqkv_t + 2304LL * 2048, 2048, 128);
  transpose_w_kernel<<<dim3(64, 64, 1), tb, 0, stream>>>(o_w, o_wt, 2048, 2048);
  transpose_w_kernel<<<dim3(172, 64, 1), tb, 0, stream>>>(gate_w, g_t, 2048, 5504);
  transpose_w_kernel<<<dim3(172, 64, 1), tb, 0, stream>>>(up_w, u_t, 2048, 5504);
  transpose_w_kernel<<<dim3(64, 172, 1), tb, 0, stream>>>(down_w, d_t, 5504, 2048);
  concat_bias_kernel<<<10, 256, 0, stream>>>(q_b, k_b, v_b, bias_qkv);

  // ln1 -> h
  rmsnorm_kernel<<<4096, 256, 0, stream>>>(x, ln1, hbuf);
  // qkv = h @ Wqkv^T + bias  (M=4096, N=2560, K=2048)
  gemm_bt_kernel<0><<<dim3(20, 32), 256, 0, stream>>>(hbuf, wqkv_t, qkv, bias_qkv, 4096, 2560, 2048);
  // rope + layout
  rope_q_kernel<<<16384, 256, 0, stream>>>(qkv, pos, Qb);
  rope_k_kernel<<<2048, 256, 0, stream>>>(qkv, pos, Kb);
  v_store_kernel<<<4096, 256, 0, stream>>>(qkv, Vt);
  // attention
  attn_kernel<<<dim3(32, 32), 256, 0, stream>>>(Qb, Kb, Vt, attnb);
  // res = attn @ o_w^T + x  -> out (f32)
  gemm_bt_kernel<1><<<dim3(16, 32), 256, 0, stream>>>(attnb, o_wt, out, x, 4096, 2048, 2048);
  // ln2 -> h2 (reuse hbuf)
  rmsnorm_kernel<<<4096, 256, 0, stream>>>(out, ln2, hbuf);
  // gate / up  (M=4096, N=5504, K=2048), bf16 out
  gemm_bt_kernel<2><<<dim3(43, 32), 256, 0, stream>>>(hbuf, g_t, gbuf, nullptr, 4096, 5504, 2048);
  gemm_bt_kernel<2><<<dim3(43, 32), 256, 0, stream>>>(hbuf, u_t, ubuf, nullptr, 4096, 5504, 2048);
  // fuse = silu(g)*u  (in place over g)
  silu_mul_kernel<<<11008, 256, 0, stream>>>(gbuf, ubuf);
  // out += fuse @ down^T  (M=4096, N=2048, K=5504)
  gemm_bt_kernel<1><<<dim3(16, 32), 256, 0, stream>>>(gbuf, d_t, out, out, 4096, 2048, 5504);
}

// Round 2
// 915.391 us; speedup vs baseline: 1.1134x; 1.1134x over previous
//
#include <hip/hip_runtime.h>
#include <cstdint>
#include <cstddef>

typedef unsigned short u16;
typedef __attribute__((ext_vector_type(8))) short short8;
typedef __attribute__((ext_vector_type(4))) float f32x4;

#define DEV __device__ __forceinline__

DEV float bf2f(u16 v) { union { unsigned u; float f; } x; x.u = ((unsigned)v) << 16; return x.f; }
DEV u16 f2bf(float f) {
  union { float f; unsigned u; } x; x.f = f;
  unsigned r = x.u + 0x7fffu + ((x.u >> 16) & 1u);
  return (u16)(r >> 16);
}

DEV void gload_lds16(const void* g, void* l) {
  __builtin_amdgcn_global_load_lds((const __attribute__((address_space(1))) void*)g,
                                   (__attribute__((address_space(3))) void*)l, 16, 0, 0);
}

// ---------- transpose f32 (R x C) -> bf16 (C x R), batched over z ----------
__global__ __launch_bounds__(256) void transpose_w_kernel(
    const float* __restrict__ in, u16* __restrict__ out, int R, int C)
{
  __shared__ float tile[32][33];
  const int tx = threadIdx.x, ty = threadIdx.y;
  const int c0 = blockIdx.x * 32, r0 = blockIdx.y * 32;
  const float* inb = in + (size_t)blockIdx.z * R * C;
  u16* outb = out + (size_t)blockIdx.z * R * C;
#pragma unroll
  for (int i = 0; i < 4; ++i)
    tile[ty + i * 8][tx] = inb[(size_t)(r0 + ty + i * 8) * C + c0 + tx];
  __syncthreads();
#pragma unroll
  for (int i = 0; i < 4; ++i)
    outb[(size_t)(c0 + ty + i * 8) * R + r0 + tx] = f2bf(tile[tx][ty + i * 8]);
}

__global__ __launch_bounds__(256) void concat_bias_kernel(
    const float* __restrict__ qb, const float* __restrict__ kb,
    const float* __restrict__ vb, float* __restrict__ bias)
{
  const int i = blockIdx.x * 256 + threadIdx.x;
  if (i < 2048) bias[i] = qb[i];
  else if (i < 2304) bias[i] = kb[i - 2048];
  else if (i < 2560) bias[i] = vb[i - 2304];
}

// ---------- RMSNorm: f32 row (2048) -> bf16 ----------
__global__ __launch_bounds__(256) void rmsnorm_kernel(
    const float* __restrict__ x, const float* __restrict__ scale, u16* __restrict__ out)
{
  const int row = blockIdx.x, tid = threadIdx.x;
  const float* xr = x + (size_t)row * 2048;
  const float4 v0 = *(const float4*)&xr[tid * 8];
  const float4 v1 = *(const float4*)&xr[tid * 8 + 4];
  float ss = v0.x * v0.x + v0.y * v0.y + v0.z * v0.z + v0.w * v0.w +
             v1.x * v1.x + v1.y * v1.y + v1.z * v1.z + v1.w * v1.w;
#pragma unroll
  for (int d = 32; d > 0; d >>= 1) ss += __shfl_down(ss, d);
  __shared__ float red[4];
  if ((tid & 63) == 0) red[tid >> 6] = ss;
  __syncthreads();
  const float tot = red[0] + red[1] + red[2] + red[3];
  const float inv = rsqrtf(tot * (1.f / 2048.f) + 1e-6f);
  const float* sc = scale + tid * 8;
  short8 ov;
  ov[0] = (short)f2bf(v0.x * inv * sc[0]); ov[1] = (short)f2bf(v0.y * inv * sc[1]);
  ov[2] = (short)f2bf(v0.z * inv * sc[2]); ov[3] = (short)f2bf(v0.w * inv * sc[3]);
  ov[4] = (short)f2bf(v1.x * inv * sc[4]); ov[5] = (short)f2bf(v1.y * inv * sc[5]);
  ov[6] = (short)f2bf(v1.z * inv * sc[6]); ov[7] = (short)f2bf(v1.w * inv * sc[7]);
  *(short8*)&out[(size_t)row * 2048 + tid * 8] = ov;
}

// ---------- GEMM: C(MxN) = A(MxK,bf16) @ Bt(NxK,bf16)^T, m97 structure ----------
// MODE 0: C f32 = acc + bias[col]; MODE 1: C f32 = acc + aux[idx]; MODE 2: C bf16 = acc
template <int MODE>
__global__ __launch_bounds__(256) void gemm_bt_kernel(
    const u16* __restrict__ A, const u16* __restrict__ Bt,
    void* C, const float* aux, int M, int N, int K)
{
  __shared__ u16 As[128 * 64];
  __shared__ u16 Bs[128 * 64];
  const int tid = threadIdx.x;
  const int wave = tid >> 6, lane = tid & 63, lo = lane & 15, hi = lane >> 4;
  const int wm = wave >> 1, wn = wave & 1;
  const int row0 = blockIdx.y * 128, col0 = blockIdx.x * 128;

  const f32x4 fz = {0.f, 0.f, 0.f, 0.f};
  f32x4 acc[4][4];
#pragma unroll
  for (int a = 0; a < 4; ++a)
#pragma unroll
    for (int b = 0; b < 4; ++b) acc[a][b] = fz;

  const u16* Ag = A + (size_t)(row0 + (tid >> 3)) * K + (tid & 7) * 8;
  const u16* Bg = Bt + (size_t)(col0 + (tid >> 3)) * K + (tid & 7) * 8;
  u16* lA = &As[wave * 512];
  u16* lB = &Bs[wave * 512];

  for (int kt = 0; kt < K; kt += 64) {
#pragma unroll
    for (int i = 0; i < 4; ++i) {
      gload_lds16(Ag + (size_t)i * 32 * K + kt, lA + i * 2048);
      gload_lds16(Bg + (size_t)i * 32 * K + kt, lB + i * 2048);
    }
    __syncthreads();
#pragma unroll
    for (int kc = 0; kc < 2; ++kc) {
      short8 af[4], bfr[4];
#pragma unroll
      for (int mt = 0; mt < 4; ++mt)
        af[mt] = *(const short8*)&As[(wm * 64 + mt * 16 + lo) * 64 + kc * 32 + hi * 8];
#pragma unroll
      for (int nt = 0; nt < 4; ++nt)
        bfr[nt] = *(const short8*)&Bs[(wn * 64 + nt * 16 + lo) * 64 + kc * 32 + hi * 8];
#pragma unroll
      for (int mt = 0; mt < 4; ++mt)
#pragma unroll
        for (int nt = 0; nt < 4; ++nt)
          acc[mt][nt] = __builtin_amdgcn_mfma_f32_16x16x32_bf16(af[mt], bfr[nt], acc[mt][nt], 0, 0, 0);
    }
    __syncthreads();
  }

  float* Cf = (float*)C;
  u16* Ch = (u16*)C;
#pragma unroll
  for (int mt = 0; mt < 4; ++mt) {
#pragma unroll
    for (int nt = 0; nt < 4; ++nt) {
      const int col = col0 + wn * 64 + nt * 16 + lo;
#pragma unroll
      for (int j = 0; j < 4; ++j) {
        const int row = row0 + wm * 64 + mt * 16 + hi * 4 + j;
        const size_t idx = (size_t)row * N + col;
        const float v = acc[mt][nt][j];
        if (MODE == 0) Cf[idx] = v + aux[col];
        else if (MODE == 1) Cf[idx] = v + aux[idx];
        else Ch[idx] = f2bf(v);
      }
    }
  }
}

// ---------- RoPE q: qkv f32 (4096 x 2560) -> Qb bf16 (B,N,T,H), scaled ----------
// scale = 1/sqrt(128) * log2(e)  (softmax done in exp2 domain)
__global__ __launch_bounds__(256) void rope_q_kernel(
    const float* __restrict__ qkv, const int* __restrict__ pos, u16* __restrict__ Qb)
{
  const int idx = blockIdx.x * 256 + threadIdx.x;  // 4096*1024
  const int bt = idx >> 10;
  const int rem = idx & 1023;
  const int n = rem >> 6, hp = rem & 63;
  const int t = bt & 2047, b = bt >> 11;
  const float x1 = qkv[(size_t)bt * 2560 + n * 128 + hp];
  const float x2 = qkv[(size_t)bt * 2560 + n * 128 + hp + 64];
  const float inv = exp2f((float)hp * (-19.931568569324174f / 64.f));
  const float ang = (float)pos[t] * inv;
  float s, c;
  sincosf(ang, &s, &c);
  const float sc = 0.08838834764831845f * 1.4426950408889634f;
  const size_t base = ((size_t)(b * 16 + n) * 2048 + t) * 128 + hp;
  Qb[base] = f2bf((x1 * c - x2 * s) * sc);
  Qb[base + 64] = f2bf((x2 * c + x1 * s) * sc);
}

__global__ __launch_bounds__(256) void rope_k_kernel(
    const float* __restrict__ qkv, const int* __restrict__ pos, u16* __restrict__ Kb)
{
  const int idx = blockIdx.x * 256 + threadIdx.x;  // 4096*128
  const int bt = idx >> 7;
  const int rem = idx & 127;
  const int kh = rem >> 6, hp = rem & 63;
  const int t = bt & 2047, b = bt >> 11;
  const float x1 = qkv[(size_t)bt * 2560 + 2048 + kh * 128 + hp];
  const float x2 = qkv[(size_t)bt * 2560 + 2048 + kh * 128 + hp + 64];
  const float inv = exp2f((float)hp * (-19.931568569324174f / 64.f));
  const float ang = (float)pos[t] * inv;
  float s, c;
  sincosf(ang, &s, &c);
  const size_t base = ((size_t)(b * 2 + kh) * 2048 + t) * 128 + hp;
  Kb[base] = f2bf(x1 * c - x2 * s);
  Kb[base + 64] = f2bf(x2 * c + x1 * s);
}

// ---------- V: qkv f32 -> Vt bf16 (B,KH,H,T) transposed ----------
__global__ __launch_bounds__(256) void v_store_kernel(
    const float* __restrict__ qkv, u16* __restrict__ Vt)
{
  const int idx = blockIdx.x * 256 + threadIdx.x;  // 4096*256
  const int bt = idx >> 8;
  const int rem = idx & 255;
  const int kh = rem >> 7, hh = rem & 127;
  const int t = bt & 2047, b = bt >> 11;
  const float v = qkv[(size_t)bt * 2560 + 2304 + kh * 128 + hh];
  Vt[((size_t)((b * 2 + kh) * 128 + hh)) * 2048 + t] = f2bf(v);
}

// ---------- flash attention, causal, GQA group 8 ----------
// T2 XOR-swizzle (byte ^= (row&7)<<4) on K/V/P tiles; rule-21: linear LDS dest
// for global_load_lds + inverse-swizzled GLOBAL source col + swizzled reads.
// 2-phase double-buffer: STAGE(t+1); compute(t); one __syncthreads per tile.
__global__ __launch_bounds__(256) void attn_kernel(
    const u16* __restrict__ Qb, const u16* __restrict__ Kb,
    const u16* __restrict__ Vt, u16* __restrict__ Out)
{
  __shared__ u16 Ks[2][64 * 128];
  __shared__ u16 Vs[2][128 * 64];
  __shared__ u16 Ps[4][16 * 64];
  const int tid = threadIdx.x;
  const int wave = tid >> 6, lane = tid & 63, lo = lane & 15, hi = lane >> 4;
  const int q0 = (int)(gridDim.x - 1 - blockIdx.x) * 64;  // heavy tiles first
  const int bn = blockIdx.y;
  const int b = bn >> 4, n = bn & 15, kh = n >> 3;

  const u16* qptr = Qb + ((size_t)((b * 16 + n) * 2048) + q0 + wave * 16 + lo) * 128;
  short8 qf[4];
#pragma unroll
  for (int kc = 0; kc < 4; ++kc) qf[kc] = *(const short8*)&qptr[kc * 32 + hi * 8];

  const f32x4 fz = {0.f, 0.f, 0.f, 0.f};
  float m_r[4], l_r[4];
  f32x4 oacc[8];
#pragma unroll
  for (int j = 0; j < 4; ++j) { m_r[j] = -1e30f; l_r[j] = 0.f; }
#pragma unroll
  for (int ht = 0; ht < 8; ++ht) oacc[ht] = fz;

  const u16* kg = Kb + (size_t)(b * 2 + kh) * 2048 * 128;
  const u16* vg = Vt + (size_t)(b * 2 + kh) * 128 * 2048;
  const int nblk = q0 / 64 + 1;

  const int kr = tid >> 4, kcb = (tid & 15) * 16;   // K stage: row, linear col byte
  const int vr = tid >> 3, vcb = (tid & 7) * 16;    // V stage: row, linear col byte

  auto STAGE = [&](int buf, int s0) {
    u16* lK = &Ks[buf][wave * 512];
    u16* lV = &Vs[buf][wave * 512];
#pragma unroll
    for (int i = 0; i < 4; ++i) {
      const int rk = i * 16 + kr;
      const int ck = (kcb ^ ((rk & 7) << 4)) >> 1;       // inverse-swizzled source col
      gload_lds16(kg + (size_t)(s0 + rk) * 128 + ck, lK + i * 2048);
      const int rv = i * 32 + vr;
      const int cv = (vcb ^ ((rv & 7) << 4)) >> 1;
      gload_lds16(vg + (size_t)rv * 2048 + s0 + cv, lV + i * 2048);
    }
  };

  STAGE(0, 0);
  __syncthreads();

  int cur = 0;
  for (int sb = 0; sb < nblk; ++sb) {
    const int s0 = sb * 64;
    if (sb + 1 < nblk) STAGE(cur ^ 1, s0 + 64);

    float sall[4][4];
    __builtin_amdgcn_s_setprio(1);
#pragma unroll
    for (int st = 0; st < 4; ++st) {
      f32x4 s = fz;
#pragma unroll
      for (int kc = 0; kc < 4; ++kc) {
        const int row = st * 16 + lo;
        const int cb = (kc * 64 + hi * 16) ^ ((lo & 7) << 4);
        short8 kf = *(const short8*)&Ks[cur][row * 128 + (cb >> 1)];
        s = __builtin_amdgcn_mfma_f32_16x16x32_bf16(qf[kc], kf, s, 0, 0, 0);
      }
#pragma unroll
      for (int j = 0; j < 4; ++j) sall[st][j] = s[j];
    }
    __builtin_amdgcn_s_setprio(0);

    if (sb == nblk - 1) {
#pragma unroll
      for (int st = 0; st < 4; ++st) {
        const int sg = s0 + st * 16 + lo;
#pragma unroll
        for (int j = 0; j < 4; ++j) {
          const int qg = q0 + wave * 16 + hi * 4 + j;
          if (sg > qg) sall[st][j] = -1e30f;
        }
      }
    }

    float alpha[4];
#pragma unroll
    for (int j = 0; j < 4; ++j) {
      float t = fmaxf(fmaxf(sall[0][j], sall[1][j]), fmaxf(sall[2][j], sall[3][j]));
      t = fmaxf(t, __shfl_xor(t, 1));
      t = fmaxf(t, __shfl_xor(t, 2));
      t = fmaxf(t, __shfl_xor(t, 4));
      t = fmaxf(t, __shfl_xor(t, 8));
      const float mnew = fmaxf(m_r[j], t);
      alpha[j] = exp2f(m_r[j] - mnew);   // scores pre-scaled by log2(e)
      m_r[j] = mnew;
    }

    float rsum[4] = {0.f, 0.f, 0.f, 0.f};
#pragma unroll
    for (int st = 0; st < 4; ++st) {
#pragma unroll
      for (int j = 0; j < 4; ++j) {
        const float p = exp2f(sall[st][j] - m_r[j]);
        rsum[j] += p;
        const int row = hi * 4 + j;
        const int cbp = (st * 32 + lo * 2) ^ ((row & 7) << 4);
        Ps[wave][row * 64 + (cbp >> 1)] = f2bf(p);
      }
    }
#pragma unroll
    for (int j = 0; j < 4; ++j) {
      float rs = rsum[j];
      rs += __shfl_xor(rs, 1);
      rs += __shfl_xor(rs, 2);
      rs += __shfl_xor(rs, 4);
      rs += __shfl_xor(rs, 8);
      l_r[j] = l_r[j] * alpha[j] + rs;
    }
#pragma unroll
    for (int ht = 0; ht < 8; ++ht) {
#pragma unroll
      for (int j = 0; j < 4; ++j) oacc[ht][j] *= alpha[j];
    }

    asm volatile("s_waitcnt lgkmcnt(0)" ::: "memory");
    __builtin_amdgcn_sched_barrier(0);

    const int pcb0 = (hi * 16) ^ ((lo & 7) << 4);
    const int pcb1 = (64 + hi * 16) ^ ((lo & 7) << 4);
    const short8 pf0 = *(const short8*)&Ps[wave][lo * 64 + (pcb0 >> 1)];
    const short8 pf1 = *(const short8*)&Ps[wave][lo * 64 + (pcb1 >> 1)];
    __builtin_amdgcn_s_setprio(1);
#pragma unroll
    for (int ht = 0; ht < 8; ++ht) {
      const int row = ht * 16 + lo;
      const int cb0 = (hi * 16) ^ ((row & 7) << 4);
      const int cb1 = (64 + hi * 16) ^ ((row & 7) << 4);
      const short8 vf0 = *(const short8*)&Vs[cur][row * 64 + (cb0 >> 1)];
      const short8 vf1 = *(const short8*)&Vs[cur][row * 64 + (cb1 >> 1)];
      oacc[ht] = __builtin_amdgcn_mfma_f32_16x16x32_bf16(pf0, vf0, oacc[ht], 0, 0, 0);
      oacc[ht] = __builtin_amdgcn_mfma_f32_16x16x32_bf16(pf1, vf1, oacc[ht], 0, 0, 0);
    }
    __builtin_amdgcn_s_setprio(0);

    if (sb + 1 < nblk) __syncthreads();
    cur ^= 1;
  }

#pragma unroll
  for (int j = 0; j < 4; ++j) {
    const float inv = 1.0f / l_r[j];
    const int trow = q0 + wave * 16 + hi * 4 + j;
    const size_t base = ((size_t)(b * 2048 + trow)) * 2048 + n * 128;
#pragma unroll
    for (int ht = 0; ht < 8; ++ht)
      Out[base + ht * 16 + lo] = f2bf(oacc[ht][j] * inv);
  }
}

// ---------- SwiGLU combine: g = silu(g) * u (bf16, in-place over g) ----------
__global__ __launch_bounds__(256) void silu_mul_kernel(
    u16* __restrict__ g, const u16* __restrict__ u)
{
  const size_t i = ((size_t)blockIdx.x * 256 + threadIdx.x) * 8;
  short8 gv = *(const short8*)&g[i];
  const short8 uv = *(const short8*)&u[i];
#pragma unroll
  for (int j = 0; j < 8; ++j) {
    const float xg = bf2f((u16)gv[j]);
    const float xu = bf2f((u16)uv[j]);
    const float s = xg / (1.f + __expf(-xg));
    gv[j] = (short)f2bf(s * xu);
  }
  *(short8*)&g[i] = gv;
}

extern "C" void kernel_launch(void* const* d_in, const int* in_sizes, int n_in,
                              void* d_out, int out_size, void* d_ws, size_t ws_size,
                              hipStream_t stream)
{
  const float* x      = (const float*)d_in[0];
  const int*   pos    = (const int*)d_in[1];
  const float* ln1    = (const float*)d_in[2];
  const float* q_w    = (const float*)d_in[3];
  const float* q_b    = (const float*)d_in[4];
  const float* k_w    = (const float*)d_in[5];
  const float* k_b    = (const float*)d_in[6];
  const float* v_w    = (const float*)d_in[7];
  const float* v_b    = (const float*)d_in[8];
  const float* o_w    = (const float*)d_in[9];
  const float* ln2    = (const float*)d_in[10];
  const float* gate_w = (const float*)d_in[11];
  const float* up_w   = (const float*)d_in[12];
  const float* down_w = (const float*)d_in[13];
  float* out = (float*)d_out;

  char* w = (char*)d_ws;
  u16* wqkv_t = (u16*)w;       w += 2560LL * 2048 * 2;   // (N*H+KH*H*2) x D, bf16
  u16* o_wt   = (u16*)w;       w += 2048LL * 2048 * 2;   // D x (N*H)
  u16* g_t    = (u16*)w;       w += 5504LL * 2048 * 2;   // I x D
  u16* u_t    = (u16*)w;       w += 5504LL * 2048 * 2;   // I x D
  u16* d_t    = (u16*)w;       w += 2048LL * 5504 * 2;   // D x I
  u16* hbuf   = (u16*)w;       w += 4096LL * 2048 * 2;   // h / h2 bf16
  float* bias_qkv = (float*)w; w += 2560 * 4;
  char* un = w;  // union region: phase1 (qkv/Qb/Kb/Vt/attn) then phase2 (g/u)
  float* qkv  = (float*)un;                                            // 4096x2560 f32
  u16*  Qb    = (u16*)(un + 41943040LL);                               // (B,N,T,H)
  u16*  Kb    = (u16*)(un + 41943040LL + 16777216LL);                  // (B,KH,T,H)
  u16*  Vt    = (u16*)(un + 41943040LL + 16777216LL + 2097152LL);      // (B,KH,H,T)
  u16*  attnb = (u16*)(un + 41943040LL + 16777216LL + 2097152LL + 2097152LL); // (B,T,N*H)
  u16*  gbuf  = (u16*)un;                                              // 4096x5504 bf16
  u16*  ubuf  = (u16*)(un + 45088768LL);                               // 4096x5504 bf16

  const dim3 tb(32, 8);
  // weight convert + transpose (f32 -> bf16, B^T layout)
  transpose_w_kernel<<<dim3(4, 64, 16), tb, 0, stream>>>(q_w, wqkv_t, 2048, 128);
  transpose_w_kernel<<<dim3(4, 64, 2),  tb, 0, stream>>>(k_w, wqkv_t + 2048LL * 2048, 2048, 128);
  transpose_w_kernel<<<dim3(4, 64, 2),  tb, 0, stream>>>(v_w, wqkv_t + 2304LL * 2048, 2048, 128);
  transpose_w_kernel<<<dim3(64, 64, 1), tb, 0, stream>>>(o_w, o_wt, 2048, 2048);
  transpose_w_kernel<<<dim3(172, 64, 1), tb, 0, stream>>>(gate_w, g_t, 2048, 5504);
  transpose_w_kernel<<<dim3(172, 64, 1), tb, 0, stream>>>(up_w, u_t, 2048, 5504);
  transpose_w_kernel<<<dim3(64, 172, 1), tb, 0, stream>>>(down_w, d_t, 5504, 2048);
  concat_bias_kernel<<<10, 256, 0, stream>>>(q_b, k_b, v_b, bias_qkv);

  // ln1 -> h
  rmsnorm_kernel<<<4096, 256, 0, stream>>>(x, ln1, hbuf);
  // qkv = h @ Wqkv^T + bias  (M=4096, N=2560, K=2048)
  gemm_bt_kernel<0><<<dim3(20, 32), 256, 0, stream>>>(hbuf, wqkv_t, qkv, bias_qkv, 4096, 2560, 2048);
  // rope + layout
  rope_q_kernel<<<16384, 256, 0, stream>>>(qkv, pos, Qb);
  rope_k_kernel<<<2048, 256, 0, stream>>>(qkv, pos, Kb);
  v_store_kernel<<<4096, 256, 0, stream>>>(qkv, Vt);
  // attention
  attn_kernel<<<dim3(32, 32), 256, 0, stream>>>(Qb, Kb, Vt, attnb);
  // res = attn @ o_w^T + x  -> out (f32)
  gemm_bt_kernel<1><<<dim3(16, 32), 256, 0, stream>>>(attnb, o_wt, out, x, 4096, 2048, 2048);
  // ln2 -> h2 (reuse hbuf)
  rmsnorm_kernel<<<4096, 256, 0, stream>>>(out, ln2, hbuf);
  // gate / up  (M=4096, N=5504, K=2048), bf16 out
  gemm_bt_kernel<2><<<dim3(43, 32), 256, 0, stream>>>(hbuf, g_t, gbuf, nullptr, 4096, 5504, 2048);
  gemm_bt_kernel<2><<<dim3(43, 32), 256, 0, stream>>>(hbuf, u_t, ubuf, nullptr, 4096, 5504, 2048);
  // fuse = silu(g)*u  (in place over g)
  silu_mul_kernel<<<11008, 256, 0, stream>>>(gbuf, ubuf);
  // out += fuse @ down^T  (M=4096, N=2048, K=5504)
  gemm_bt_kernel<1><<<dim3(16, 32), 256, 0, stream>>>(gbuf, d_t, out, out, 4096, 2048, 5504);
}

// Round 3
// 830.815 us; speedup vs baseline: 1.2267x; 1.1018x over previous
//
#include <hip/hip_runtime.h>
#include <cstdint>
#include <cstddef>

typedef unsigned short u16;
typedef __attribute__((ext_vector_type(8))) short short8;
typedef __attribute__((ext_vector_type(4))) float f32x4;

#define DEV __device__ __forceinline__

DEV float bf2f(u16 v) { union { unsigned u; float f; } x; x.u = ((unsigned)v) << 16; return x.f; }
DEV u16 f2bf(float f) {
  union { float f; unsigned u; } x; x.f = f;
  unsigned r = x.u + 0x7fffu + ((x.u >> 16) & 1u);
  return (u16)(r >> 16);
}

DEV void gload_lds16(const void* g, void* l) {
  __builtin_amdgcn_global_load_lds((const __attribute__((address_space(1))) void*)g,
                                   (__attribute__((address_space(3))) void*)l, 16, 0, 0);
}

// ---------- transpose f32 (R x C) -> bf16 (C x R), batched over z ----------
__global__ __launch_bounds__(256) void transpose_w_kernel(
    const float* __restrict__ in, u16* __restrict__ out, int R, int C)
{
  __shared__ float tile[32][33];
  const int tx = threadIdx.x, ty = threadIdx.y;
  const int c0 = blockIdx.x * 32, r0 = blockIdx.y * 32;
  const float* inb = in + (size_t)blockIdx.z * R * C;
  u16* outb = out + (size_t)blockIdx.z * R * C;
#pragma unroll
  for (int i = 0; i < 4; ++i)
    tile[ty + i * 8][tx] = inb[(size_t)(r0 + ty + i * 8) * C + c0 + tx];
  __syncthreads();
#pragma unroll
  for (int i = 0; i < 4; ++i)
    outb[(size_t)(c0 + ty + i * 8) * R + r0 + tx] = f2bf(tile[tx][ty + i * 8]);
}

__global__ __launch_bounds__(256) void concat_bias_kernel(
    const float* __restrict__ qb, const float* __restrict__ kb,
    const float* __restrict__ vb, float* __restrict__ bias)
{
  const int i = blockIdx.x * 256 + threadIdx.x;
  if (i < 2048) bias[i] = qb[i];
  else if (i < 2304) bias[i] = kb[i - 2048];
  else if (i < 2560) bias[i] = vb[i - 2304];
}

// ---------- RMSNorm: f32 row (2048) -> bf16 ----------
__global__ __launch_bounds__(256) void rmsnorm_kernel(
    const float* __restrict__ x, const float* __restrict__ scale, u16* __restrict__ out)
{
  const int row = blockIdx.x, tid = threadIdx.x;
  const float* xr = x + (size_t)row * 2048;
  const float4 v0 = *(const float4*)&xr[tid * 8];
  const float4 v1 = *(const float4*)&xr[tid * 8 + 4];
  float ss = v0.x * v0.x + v0.y * v0.y + v0.z * v0.z + v0.w * v0.w +
             v1.x * v1.x + v1.y * v1.y + v1.z * v1.z + v1.w * v1.w;
#pragma unroll
  for (int d = 32; d > 0; d >>= 1) ss += __shfl_down(ss, d);
  __shared__ float red[4];
  if ((tid & 63) == 0) red[tid >> 6] = ss;
  __syncthreads();
  const float tot = red[0] + red[1] + red[2] + red[3];
  const float inv = rsqrtf(tot * (1.f / 2048.f) + 1e-6f);
  const float* sc = scale + tid * 8;
  short8 ov;
  ov[0] = (short)f2bf(v0.x * inv * sc[0]); ov[1] = (short)f2bf(v0.y * inv * sc[1]);
  ov[2] = (short)f2bf(v0.z * inv * sc[2]); ov[3] = (short)f2bf(v0.w * inv * sc[3]);
  ov[4] = (short)f2bf(v1.x * inv * sc[4]); ov[5] = (short)f2bf(v1.y * inv * sc[5]);
  ov[6] = (short)f2bf(v1.z * inv * sc[6]); ov[7] = (short)f2bf(v1.w * inv * sc[7]);
  *(short8*)&out[(size_t)row * 2048 + tid * 8] = ov;
}

// ---------- GEMM: C(MxN) = A(MxK,bf16) @ Bt(NxK,bf16)^T, m97 structure ----------
// MODE 0: C f32 = acc + bias[col]; MODE 1: C f32 = acc + aux[idx]; MODE 2: C bf16 = acc
template <int MODE>
__global__ __launch_bounds__(256) void gemm_bt_kernel(
    const u16* __restrict__ A, const u16* __restrict__ Bt,
    void* C, const float* aux, int M, int N, int K)
{
  __shared__ u16 As[128 * 64];
  __shared__ u16 Bs[128 * 64];
  const int tid = threadIdx.x;
  const int wave = tid >> 6, lane = tid & 63, lo = lane & 15, hi = lane >> 4;
  const int wm = wave >> 1, wn = wave & 1;
  const int row0 = blockIdx.y * 128, col0 = blockIdx.x * 128;

  const f32x4 fz = {0.f, 0.f, 0.f, 0.f};
  f32x4 acc[4][4];
#pragma unroll
  for (int a = 0; a < 4; ++a)
#pragma unroll
    for (int b = 0; b < 4; ++b) acc[a][b] = fz;

  const u16* Ag = A + (size_t)(row0 + (tid >> 3)) * K + (tid & 7) * 8;
  const u16* Bg = Bt + (size_t)(col0 + (tid >> 3)) * K + (tid & 7) * 8;
  u16* lA = &As[wave * 512];
  u16* lB = &Bs[wave * 512];

  for (int kt = 0; kt < K; kt += 64) {
#pragma unroll
    for (int i = 0; i < 4; ++i) {
      gload_lds16(Ag + (size_t)i * 32 * K + kt, lA + i * 2048);
      gload_lds16(Bg + (size_t)i * 32 * K + kt, lB + i * 2048);
    }
    __syncthreads();
#pragma unroll
    for (int kc = 0; kc < 2; ++kc) {
      short8 af[4], bfr[4];
#pragma unroll
      for (int mt = 0; mt < 4; ++mt)
        af[mt] = *(const short8*)&As[(wm * 64 + mt * 16 + lo) * 64 + kc * 32 + hi * 8];
#pragma unroll
      for (int nt = 0; nt < 4; ++nt)
        bfr[nt] = *(const short8*)&Bs[(wn * 64 + nt * 16 + lo) * 64 + kc * 32 + hi * 8];
#pragma unroll
      for (int mt = 0; mt < 4; ++mt)
#pragma unroll
        for (int nt = 0; nt < 4; ++nt)
          acc[mt][nt] = __builtin_amdgcn_mfma_f32_16x16x32_bf16(af[mt], bfr[nt], acc[mt][nt], 0, 0, 0);
    }
    __syncthreads();
  }

  float* Cf = (float*)C;
  u16* Ch = (u16*)C;
#pragma unroll
  for (int mt = 0; mt < 4; ++mt) {
#pragma unroll
    for (int nt = 0; nt < 4; ++nt) {
      const int col = col0 + wn * 64 + nt * 16 + lo;
#pragma unroll
      for (int j = 0; j < 4; ++j) {
        const int row = row0 + wm * 64 + mt * 16 + hi * 4 + j;
        const size_t idx = (size_t)row * N + col;
        const float v = acc[mt][nt][j];
        if (MODE == 0) Cf[idx] = v + aux[col];
        else if (MODE == 1) Cf[idx] = v + aux[idx];
        else Ch[idx] = f2bf(v);
      }
    }
  }
}

// ---------- RoPE q: qkv f32 (4096 x 2560) -> Qb bf16 (B,N,T,H), scaled ----------
// scale = 1/sqrt(128) * log2(e)  (softmax done in exp2 domain)
__global__ __launch_bounds__(256) void rope_q_kernel(
    const float* __restrict__ qkv, const int* __restrict__ pos, u16* __restrict__ Qb)
{
  const int idx = blockIdx.x * 256 + threadIdx.x;  // 4096*1024
  const int bt = idx >> 10;
  const int rem = idx & 1023;
  const int n = rem >> 6, hp = rem & 63;
  const int t = bt & 2047, b = bt >> 11;
  const float x1 = qkv[(size_t)bt * 2560 + n * 128 + hp];
  const float x2 = qkv[(size_t)bt * 2560 + n * 128 + hp + 64];
  const float inv = exp2f((float)hp * (-19.931568569324174f / 64.f));
  const float ang = (float)pos[t] * inv;
  float s, c;
  sincosf(ang, &s, &c);
  const float sc = 0.08838834764831845f * 1.4426950408889634f;
  const size_t base = ((size_t)(b * 16 + n) * 2048 + t) * 128 + hp;
  Qb[base] = f2bf((x1 * c - x2 * s) * sc);
  Qb[base + 64] = f2bf((x2 * c + x1 * s) * sc);
}

__global__ __launch_bounds__(256) void rope_k_kernel(
    const float* __restrict__ qkv, const int* __restrict__ pos, u16* __restrict__ Kb)
{
  const int idx = blockIdx.x * 256 + threadIdx.x;  // 4096*128
  const int bt = idx >> 7;
  const int rem = idx & 127;
  const int kh = rem >> 6, hp = rem & 63;
  const int t = bt & 2047, b = bt >> 11;
  const float x1 = qkv[(size_t)bt * 2560 + 2048 + kh * 128 + hp];
  const float x2 = qkv[(size_t)bt * 2560 + 2048 + kh * 128 + hp + 64];
  const float inv = exp2f((float)hp * (-19.931568569324174f / 64.f));
  const float ang = (float)pos[t] * inv;
  float s, c;
  sincosf(ang, &s, &c);
  const size_t base = ((size_t)(b * 2 + kh) * 2048 + t) * 128 + hp;
  Kb[base] = f2bf(x1 * c - x2 * s);
  Kb[base + 64] = f2bf(x2 * c + x1 * s);
}

// ---------- V: qkv f32 -> Vt bf16 (B,KH,H,T) transposed ----------
__global__ __launch_bounds__(256) void v_store_kernel(
    const float* __restrict__ qkv, u16* __restrict__ Vt)
{
  const int idx = blockIdx.x * 256 + threadIdx.x;  // 4096*256
  const int bt = idx >> 8;
  const int rem = idx & 255;
  const int kh = rem >> 7, hh = rem & 127;
  const int t = bt & 2047, b = bt >> 11;
  const float v = qkv[(size_t)bt * 2560 + 2304 + kh * 128 + hh];
  Vt[((size_t)((b * 2 + kh) * 128 + hh)) * 2048 + t] = f2bf(v);
}

// ---------- flash attention, causal, GQA group 8 ----------
// T2 XOR-swizzle on K/V/P; 2-phase dbuf; causal PAIRING: block x handles
// q-tiles {31-x, x} -> every block does exactly 33 KV-tiles (load balance).
// T13 defer-rescale; native v_exp_f32 (scores pre-scaled by log2(e)).
__global__ __launch_bounds__(256) void attn_kernel(
    const u16* __restrict__ Qb, const u16* __restrict__ Kb,
    const u16* __restrict__ Vt, u16* __restrict__ Out)
{
  __shared__ u16 Ks[2][64 * 128];
  __shared__ u16 Vs[2][128 * 64];
  __shared__ u16 Ps[4][16 * 64];
  const int tid = threadIdx.x;
  const int wave = tid >> 6, lane = tid & 63, lo = lane & 15, hi = lane >> 4;
  const int bn = blockIdx.y;
  const int b = bn >> 4, n = bn & 15, kh = n >> 3;

  const f32x4 fz = {0.f, 0.f, 0.f, 0.f};
  const u16* kg = Kb + (size_t)(b * 2 + kh) * 2048 * 128;
  const u16* vg = Vt + (size_t)(b * 2 + kh) * 128 * 2048;

  const int kr = tid >> 4, kcb = (tid & 15) * 16;   // K stage: row, linear col byte
  const int vr = tid >> 3, vcb = (tid & 7) * 16;    // V stage: row, linear col byte

  auto STAGE = [&](int buf, int s0) {
    u16* lK = &Ks[buf][wave * 512];
    u16* lV = &Vs[buf][wave * 512];
#pragma unroll
    for (int i = 0; i < 4; ++i) {
      const int rk = i * 16 + kr;
      const int ck = (kcb ^ ((rk & 7) << 4)) >> 1;       // inverse-swizzled source col
      gload_lds16(kg + (size_t)(s0 + rk) * 128 + ck, lK + i * 2048);
      const int rv = i * 32 + vr;
      const int cv = (vcb ^ ((rv & 7) << 4)) >> 1;
      gload_lds16(vg + (size_t)rv * 2048 + s0 + cv, lV + i * 2048);
    }
  };

  auto processTile = [&](int q0) {
    const int nblk = q0 / 64 + 1;
    const u16* qptr = Qb + ((size_t)((b * 16 + n) * 2048) + q0 + wave * 16 + lo) * 128;
    short8 qf[4];
#pragma unroll
    for (int kc = 0; kc < 4; ++kc) qf[kc] = *(const short8*)&qptr[kc * 32 + hi * 8];

    float m_r[4], l_r[4];
    f32x4 oacc[8];
#pragma unroll
    for (int j = 0; j < 4; ++j) { m_r[j] = -1e30f; l_r[j] = 0.f; }
#pragma unroll
    for (int ht = 0; ht < 8; ++ht) oacc[ht] = fz;

    __syncthreads();      // protect buffers from previous q-tile's readers
    STAGE(0, 0);
    __syncthreads();

    int cur = 0;
    for (int sb = 0; sb < nblk; ++sb) {
      const int s0 = sb * 64;
      if (sb + 1 < nblk) STAGE(cur ^ 1, s0 + 64);

      float sall[4][4];
      __builtin_amdgcn_s_setprio(1);
#pragma unroll
      for (int st = 0; st < 4; ++st) {
        f32x4 s = fz;
#pragma unroll
        for (int kc = 0; kc < 4; ++kc) {
          const int row = st * 16 + lo;
          const int cb = (kc * 64 + hi * 16) ^ ((lo & 7) << 4);
          short8 kf = *(const short8*)&Ks[cur][row * 128 + (cb >> 1)];
          s = __builtin_amdgcn_mfma_f32_16x16x32_bf16(qf[kc], kf, s, 0, 0, 0);
        }
#pragma unroll
        for (int j = 0; j < 4; ++j) sall[st][j] = s[j];
      }
      __builtin_amdgcn_s_setprio(0);

      if (sb == nblk - 1) {
#pragma unroll
        for (int st = 0; st < 4; ++st) {
          const int sg = s0 + st * 16 + lo;
#pragma unroll
          for (int j = 0; j < 4; ++j) {
            const int qg = q0 + wave * 16 + hi * 4 + j;
            if (sg > qg) sall[st][j] = -1e30f;
          }
        }
      }

      // tile max per j (in-lane over st, then across the 16-lane lo group)
      float tmax[4];
#pragma unroll
      for (int j = 0; j < 4; ++j) {
        float t = fmaxf(fmaxf(sall[0][j], sall[1][j]), fmaxf(sall[2][j], sall[3][j]));
        t = fmaxf(t, __shfl_xor(t, 1));
        t = fmaxf(t, __shfl_xor(t, 2));
        t = fmaxf(t, __shfl_xor(t, 4));
        t = fmaxf(t, __shfl_xor(t, 8));
        tmax[j] = t;
      }
      // T13 defer-rescale: skip m-update + oacc rescale when growth <= 8 (2^8 bound on P)
      const bool defer = __all((tmax[0] - m_r[0] <= 8.f) & (tmax[1] - m_r[1] <= 8.f) &
                               (tmax[2] - m_r[2] <= 8.f) & (tmax[3] - m_r[3] <= 8.f));
      if (!defer) {
        float alpha[4];
#pragma unroll
        for (int j = 0; j < 4; ++j) {
          const float mnew = fmaxf(m_r[j], tmax[j]);
          alpha[j] = __builtin_amdgcn_exp2f(m_r[j] - mnew);
          m_r[j] = mnew;
          l_r[j] *= alpha[j];
        }
#pragma unroll
        for (int ht = 0; ht < 8; ++ht) {
#pragma unroll
          for (int j = 0; j < 4; ++j) oacc[ht][j] *= alpha[j];
        }
      }

      float rsum[4] = {0.f, 0.f, 0.f, 0.f};
#pragma unroll
      for (int st = 0; st < 4; ++st) {
#pragma unroll
        for (int j = 0; j < 4; ++j) {
          const float p = __builtin_amdgcn_exp2f(sall[st][j] - m_r[j]);
          rsum[j] += p;
          const int row = hi * 4 + j;
          const int cbp = (st * 32 + lo * 2) ^ ((row & 7) << 4);
          Ps[wave][row * 64 + (cbp >> 1)] = f2bf(p);
        }
      }
#pragma unroll
      for (int j = 0; j < 4; ++j) {
        float rs = rsum[j];
        rs += __shfl_xor(rs, 1);
        rs += __shfl_xor(rs, 2);
        rs += __shfl_xor(rs, 4);
        rs += __shfl_xor(rs, 8);
        l_r[j] += rs;
      }

      asm volatile("s_waitcnt lgkmcnt(0)" ::: "memory");
      __builtin_amdgcn_sched_barrier(0);

      const int pcb0 = (hi * 16) ^ ((lo & 7) << 4);
      const int pcb1 = (64 + hi * 16) ^ ((lo & 7) << 4);
      const short8 pf0 = *(const short8*)&Ps[wave][lo * 64 + (pcb0 >> 1)];
      const short8 pf1 = *(const short8*)&Ps[wave][lo * 64 + (pcb1 >> 1)];
      __builtin_amdgcn_s_setprio(1);
#pragma unroll
      for (int ht = 0; ht < 8; ++ht) {
        const int row = ht * 16 + lo;
        const int cb0 = (hi * 16) ^ ((row & 7) << 4);
        const int cb1 = (64 + hi * 16) ^ ((row & 7) << 4);
        const short8 vf0 = *(const short8*)&Vs[cur][row * 64 + (cb0 >> 1)];
        const short8 vf1 = *(const short8*)&Vs[cur][row * 64 + (cb1 >> 1)];
        oacc[ht] = __builtin_amdgcn_mfma_f32_16x16x32_bf16(pf0, vf0, oacc[ht], 0, 0, 0);
        oacc[ht] = __builtin_amdgcn_mfma_f32_16x16x32_bf16(pf1, vf1, oacc[ht], 0, 0, 0);
      }
      __builtin_amdgcn_s_setprio(0);

      if (sb + 1 < nblk) __syncthreads();
      cur ^= 1;
    }

#pragma unroll
    for (int j = 0; j < 4; ++j) {
      const float inv = 1.0f / l_r[j];
      const int trow = q0 + wave * 16 + hi * 4 + j;
      const size_t base = ((size_t)(b * 2048 + trow)) * 2048 + n * 128;
#pragma unroll
      for (int ht = 0; ht < 8; ++ht)
        Out[base + ht * 16 + lo] = f2bf(oacc[ht][j] * inv);
    }
  };

  // paired q-tiles: deep (31-x) then shallow (x); every block = 33 KV-tiles
  processTile((int)(31 - blockIdx.x) * 64);
  processTile((int)blockIdx.x * 64);
}

// ---------- SwiGLU combine: g = silu(g) * u (bf16, in-place over g) ----------
__global__ __launch_bounds__(256) void silu_mul_kernel(
    u16* __restrict__ g, const u16* __restrict__ u)
{
  const size_t i = ((size_t)blockIdx.x * 256 + threadIdx.x) * 8;
  short8 gv = *(const short8*)&g[i];
  const short8 uv = *(const short8*)&u[i];
#pragma unroll
  for (int j = 0; j < 8; ++j) {
    const float xg = bf2f((u16)gv[j]);
    const float xu = bf2f((u16)uv[j]);
    const float s = xg / (1.f + __expf(-xg));
    gv[j] = (short)f2bf(s * xu);
  }
  *(short8*)&g[i] = gv;
}

extern "C" void kernel_launch(void* const* d_in, const int* in_sizes, int n_in,
                              void* d_out, int out_size, void* d_ws, size_t ws_size,
                              hipStream_t stream)
{
  const float* x      = (const float*)d_in[0];
  const int*   pos    = (const int*)d_in[1];
  const float* ln1    = (const float*)d_in[2];
  const float* q_w    = (const float*)d_in[3];
  const float* q_b    = (const float*)d_in[4];
  const float* k_w    = (const float*)d_in[5];
  const float* k_b    = (const float*)d_in[6];
  const float* v_w    = (const float*)d_in[7];
  const float* v_b    = (const float*)d_in[8];
  const float* o_w    = (const float*)d_in[9];
  const float* ln2    = (const float*)d_in[10];
  const float* gate_w = (const float*)d_in[11];
  const float* up_w   = (const float*)d_in[12];
  const float* down_w = (const float*)d_in[13];
  float* out = (float*)d_out;

  char* w = (char*)d_ws;
  u16* wqkv_t = (u16*)w;       w += 2560LL * 2048 * 2;   // (N*H+KH*H*2) x D, bf16
  u16* o_wt   = (u16*)w;       w += 2048LL * 2048 * 2;   // D x (N*H)
  u16* g_t    = (u16*)w;       w += 5504LL * 2048 * 2;   // I x D
  u16* u_t    = (u16*)w;       w += 5504LL * 2048 * 2;   // I x D
  u16* d_t    = (u16*)w;       w += 2048LL * 5504 * 2;   // D x I
  u16* hbuf   = (u16*)w;       w += 4096LL * 2048 * 2;   // h / h2 bf16
  float* bias_qkv = (float*)w; w += 2560 * 4;
  char* un = w;  // union region: phase1 (qkv/Qb/Kb/Vt/attn) then phase2 (g/u)
  float* qkv  = (float*)un;                                            // 4096x2560 f32
  u16*  Qb    = (u16*)(un + 41943040LL);                               // (B,N,T,H)
  u16*  Kb    = (u16*)(un + 41943040LL + 16777216LL);                  // (B,KH,T,H)
  u16*  Vt    = (u16*)(un + 41943040LL + 16777216LL + 2097152LL);      // (B,KH,H,T)
  u16*  attnb = (u16*)(un + 41943040LL + 16777216LL + 2097152LL + 2097152LL); // (B,T,N*H)
  u16*  gbuf  = (u16*)un;                                              // 4096x5504 bf16
  u16*  ubuf  = (u16*)(un + 45088768LL);                               // 4096x5504 bf16

  const dim3 tb(32, 8);
  // weight convert + transpose (f32 -> bf16, B^T layout)
  transpose_w_kernel<<<dim3(4, 64, 16), tb, 0, stream>>>(q_w, wqkv_t, 2048, 128);
  transpose_w_kernel<<<dim3(4, 64, 2),  tb, 0, stream>>>(k_w, wqkv_t + 2048LL * 2048, 2048, 128);
  transpose_w_kernel<<<dim3(4, 64, 2),  tb, 0, stream>>>(v_w, wqkv_t + 2304LL * 2048, 2048, 128);
  transpose_w_kernel<<<dim3(64, 64, 1), tb, 0, stream>>>(o_w, o_wt, 2048, 2048);
  transpose_w_kernel<<<dim3(172, 64, 1), tb, 0, stream>>>(gate_w, g_t, 2048, 5504);
  transpose_w_kernel<<<dim3(172, 64, 1), tb, 0, stream>>>(up_w, u_t, 2048, 5504);
  transpose_w_kernel<<<dim3(64, 172, 1), tb, 0, stream>>>(down_w, d_t, 5504, 2048);
  concat_bias_kernel<<<10, 256, 0, stream>>>(q_b, k_b, v_b, bias_qkv);

  // ln1 -> h
  rmsnorm_kernel<<<4096, 256, 0, stream>>>(x, ln1, hbuf);
  // qkv = h @ Wqkv^T + bias  (M=4096, N=2560, K=2048)
  gemm_bt_kernel<0><<<dim3(20, 32), 256, 0, stream>>>(hbuf, wqkv_t, qkv, bias_qkv, 4096, 2560, 2048);
  // rope + layout
  rope_q_kernel<<<16384, 256, 0, stream>>>(qkv, pos, Qb);
  rope_k_kernel<<<2048, 256, 0, stream>>>(qkv, pos, Kb);
  v_store_kernel<<<4096, 256, 0, stream>>>(qkv, Vt);
  // attention (paired q-tiles: grid x = 16 pairs)
  attn_kernel<<<dim3(16, 32), 256, 0, stream>>>(Qb, Kb, Vt, attnb);
  // res = attn @ o_w^T + x  -> out (f32)
  gemm_bt_kernel<1><<<dim3(16, 32), 256, 0, stream>>>(attnb, o_wt, out, x, 4096, 2048, 2048);
  // ln2 -> h2 (reuse hbuf)
  rmsnorm_kernel<<<4096, 256, 0, stream>>>(out, ln2, hbuf);
  // gate / up  (M=4096, N=5504, K=2048), bf16 out
  gemm_bt_kernel<2><<<dim3(43, 32), 256, 0, stream>>>(hbuf, g_t, gbuf, nullptr, 4096, 5504, 2048);
  gemm_bt_kernel<2><<<dim3(43, 32), 256, 0, stream>>>(hbuf, u_t, ubuf, nullptr, 4096, 5504, 2048);
  // fuse = silu(g)*u  (in place over g)
  silu_mul_kernel<<<11008, 256, 0, stream>>>(gbuf, ubuf);
  // out += fuse @ down^T  (M=4096, N=2048, K=5504)
  gemm_bt_kernel<1><<<dim3(16, 32), 256, 0, stream>>>(gbuf, d_t, out, out, 4096, 2048, 5504);
}